// Round 8
// baseline (565.106 us; speedup 1.0000x reference)
//
#include <hip/hip_runtime.h>
#include <hip/hip_bf16.h>
#include <math.h>

#define N_POOL 2048
#define D_POOL 4608

typedef __hip_bfloat16 bf16;
typedef __attribute__((ext_vector_type(8))) short bf16x8;
typedef __attribute__((ext_vector_type(4))) float f32x4;
typedef __attribute__((ext_vector_type(4))) unsigned short u16x4;

// input indices
#define IX 0
#define IPOOL 1
#define IAW0 2
#define IAB0 3
#define IAW1 4
#define IAB1 5
#define IWQ 6
#define IWK 7
#define ILOG 8
#define ITAU 9
#define IWBASE 10
#define IBBASE 11
#define IGAMMA 12
#define ILNS 13
#define ILNB 14
#define IBW0 15
#define IBB0 16
#define IBW1 17
#define IBB1 18

// ---------- helpers ----------
__device__ inline float wsum(float v) {
#pragma unroll
    for (int off = 32; off > 0; off >>= 1) v += __shfl_xor(v, off, 64);
    return v;
}
__device__ inline float ldin(const void* p, size_t i, int f) {
    if (f) return __bfloat162float(((const bf16*)p)[i]);
    return ((const float*)p)[i];
}
__device__ inline float gelu_f(float x) {
    float t = tanhf(0.7978845608028654f * (x + 0.044715f * x * x * x));
    return 0.5f * x * (1.0f + t);
}
__device__ inline unsigned short bfbits(float f) {
    __hip_bfloat16 h = __float2bfloat16(f);
    return *reinterpret_cast<unsigned short*>(&h);
}

// ---------- per-input dtype detector (insurance; inputs measured all-fp32) ----------
struct P19 { const void* p[19]; long n[19]; };

__global__ void detect_all(P19 ip, int* flags) {
    const int j = blockIdx.x;
    const unsigned short* u = (const unsigned short*)ip.p[j];
    long nelem = ip.n[j];
    long nhalf = nelem >> 1; if (nhalf < 1) nhalf = 1;
    long kstep = (nhalf + 2047) >> 11; if (kstep < 1) kstep = 1;
    int W = 0, S = 0, Z = 0, O = 0, C = 0;
    for (long k = threadIdx.x; k * kstep < nhalf; k += 256) {
        long i = k * kstep * 2;
        unsigned short ev = u[i], od = u[i + 1];
        int e = (ev >> 7) & 0xFF;
        if (ev == 0) Z++;
        else if (e >= 90 && e <= 141) S++;
        else W++;
        if (od) O++;
        C++;
    }
    __shared__ int sw[256], ss[256], sz[256], so[256], sc[256];
    sw[threadIdx.x] = W; ss[threadIdx.x] = S; sz[threadIdx.x] = Z;
    so[threadIdx.x] = O; sc[threadIdx.x] = C;
    __syncthreads();
    if (threadIdx.x == 0) {
        int tw = 0, ts = 0, tz = 0, to = 0, tc = 0;
        for (int i = 0; i < 256; i++) {
            tw += sw[i]; ts += ss[i]; tz += sz[i]; to += so[i]; tc += sc[i];
        }
        int f;
        if (tw * 16 > tc) f = 0;
        else if (ts == 0 && tw == 0) f = (to > 0) ? 0 : 1;
        else f = (ts >= tz) ? 1 : 0;
        flags[j] = f;
    }
}

// ---------- split-K 64x64 GEMM (fp32 math): atomic accumulate into pre-init C ----------
// afi == -2 means "A is bf16" (literal, no flags lookup).
template <int TRANSB>
__global__ __launch_bounds__(256) void gemm64_splitk(
    const void* __restrict__ A, int lda, int afi,
    const void* __restrict__ B, int ldb, int bfi, size_t boffs,
    float* __restrict__ C, int ldc, int KC, const int* __restrict__ flags)
{
    const int fa = (afi == -2) ? 1 : ((afi >= 0) ? flags[afi] : 0);
    const int fb = (bfi >= 0) ? flags[bfi] : 0;
    __shared__ __align__(16) float As[16][68];
    __shared__ __align__(16) float Bs[16][68];
    const int tid = threadIdx.x;
    const int tx = tid & 15, ty = tid >> 4;
    const int bx = blockIdx.x, by = blockIdx.y;
    const int kbeg = blockIdx.z * KC;
    float acc[4][4] = {};
    for (int k0 = kbeg; k0 < kbeg + KC; k0 += 16) {
#pragma unroll
        for (int i = 0; i < 4; i++) {
            int idx = tid + i * 256;
            int m = idx >> 4, kk = idx & 15;
            As[kk][m] = ldin(A, (size_t)(by * 64 + m) * lda + k0 + kk, fa);
        }
#pragma unroll
        for (int i = 0; i < 4; i++) {
            int idx = tid + i * 256;
            if (TRANSB) {
                int nn2 = idx >> 4, kk = idx & 15;
                Bs[kk][nn2] = ldin(B, boffs + (size_t)(bx * 64 + nn2) * ldb + k0 + kk, fb);
            } else {
                int kk = idx >> 6, nn2 = idx & 63;
                Bs[kk][nn2] = ldin(B, boffs + (size_t)(k0 + kk) * ldb + bx * 64 + nn2, fb);
            }
        }
        __syncthreads();
#pragma unroll
        for (int kk = 0; kk < 16; kk++) {
            float4 av4 = *(const float4*)&As[kk][ty * 4];
            float4 bv4 = *(const float4*)&Bs[kk][tx * 4];
            float av[4] = {av4.x, av4.y, av4.z, av4.w};
            float bv[4] = {bv4.x, bv4.y, bv4.z, bv4.w};
#pragma unroll
            for (int i = 0; i < 4; i++)
#pragma unroll
                for (int j = 0; j < 4; j++) acc[i][j] += av[i] * bv[j];
        }
        __syncthreads();
    }
#pragma unroll
    for (int i = 0; i < 4; i++) {
        int m = by * 64 + ty * 4 + i;
#pragma unroll
        for (int j = 0; j < 4; j++) {
            int n = bx * 64 + tx * 4 + j;
            atomicAdd(&C[(size_t)m * ldc + n], acc[i][j]);
        }
    }
}

// ---------- bf16 MFMA split-K GEMM, 1-wave blocks, no LDS: C += A@B^T (atomic) ----------
__global__ __launch_bounds__(64) void gemm_mfma_atomic(
    const unsigned short* __restrict__ A, int lda,
    const unsigned short* __restrict__ Bmat, int ldb,
    float* __restrict__ C, int ldc, int KC)
{
    const int m0 = blockIdx.x * 32;
    const int n0 = blockIdx.y * 64;
    const unsigned short* B = Bmat + (size_t)blockIdx.y * 64 * ldb;
    const int kbeg = blockIdx.z * KC;
    const int l = threadIdx.x;
    const int q = l >> 4, l16 = l & 15;
    f32x4 acc[2][4] = {};
    for (int k0 = kbeg; k0 < kbeg + KC; k0 += 32) {
        bf16x8 afr[2], bfr[4];
#pragma unroll
        for (int mt = 0; mt < 2; mt++)
            afr[mt] = *(const bf16x8*)&A[(size_t)(m0 + mt * 16 + l16) * lda + k0 + q * 8];
#pragma unroll
        for (int nt = 0; nt < 4; nt++)
            bfr[nt] = *(const bf16x8*)&B[(size_t)(nt * 16 + l16) * ldb + k0 + q * 8];
#pragma unroll
        for (int mt = 0; mt < 2; mt++)
#pragma unroll
            for (int nt = 0; nt < 4; nt++)
                acc[mt][nt] = __builtin_amdgcn_mfma_f32_16x16x32_bf16(
                    afr[mt], bfr[nt], acc[mt][nt], 0, 0, 0);
    }
#pragma unroll
    for (int mt = 0; mt < 2; mt++)
#pragma unroll
        for (int nt = 0; nt < 4; nt++)
#pragma unroll
            for (int r = 0; r < 4; r++) {
                int m = m0 + mt * 16 + q * 4 + r;
                atomicAdd(&C[(size_t)m * ldc + n0 + nt * 16 + l16], acc[mt][nt][r]);
            }
}

// ---------- bf16 MFMA fused GEMM, 1-wave blocks: out = act(A@B^T + bias) ----------
template <int ACT>
__global__ __launch_bounds__(64) void gemm_mfma_fused(
    const unsigned short* __restrict__ A, int lda,
    const unsigned short* __restrict__ Bmat, int ldb,
    const void* __restrict__ bias, int bifi, const int* __restrict__ flags,
    float* __restrict__ Cf, unsigned short* __restrict__ Cbf,
    int ldc, int K)
{
    const int m0 = blockIdx.x * 32;
    const int n0 = blockIdx.y * 64;
    const unsigned short* B = Bmat + (size_t)blockIdx.y * 64 * ldb;
    const int l = threadIdx.x;
    const int q = l >> 4, l16 = l & 15;
    f32x4 acc[2][4] = {};
    for (int k0 = 0; k0 < K; k0 += 32) {
        bf16x8 afr[2], bfr[4];
#pragma unroll
        for (int mt = 0; mt < 2; mt++)
            afr[mt] = *(const bf16x8*)&A[(size_t)(m0 + mt * 16 + l16) * lda + k0 + q * 8];
#pragma unroll
        for (int nt = 0; nt < 4; nt++)
            bfr[nt] = *(const bf16x8*)&B[(size_t)(nt * 16 + l16) * ldb + k0 + q * 8];
#pragma unroll
        for (int mt = 0; mt < 2; mt++)
#pragma unroll
            for (int nt = 0; nt < 4; nt++)
                acc[mt][nt] = __builtin_amdgcn_mfma_f32_16x16x32_bf16(
                    afr[mt], bfr[nt], acc[mt][nt], 0, 0, 0);
    }
    float bv[4];
#pragma unroll
    for (int nt = 0; nt < 4; nt++)
        bv[nt] = bias ? ldin(bias, n0 + nt * 16 + l16, (bifi >= 0) ? flags[bifi] : 0) : 0.f;
#pragma unroll
    for (int mt = 0; mt < 2; mt++)
#pragma unroll
        for (int nt = 0; nt < 4; nt++)
#pragma unroll
            for (int r = 0; r < 4; r++) {
                int m = m0 + mt * 16 + q * 4 + r;
                int n = n0 + nt * 16 + l16;
                float v = acc[mt][nt][r] + bv[nt];
                if (ACT == 1) v = gelu_f(v);
                if (Cf)  Cf[(size_t)m * ldc + n] = v;
                if (Cbf) Cbf[(size_t)m * ldc + n] = bfbits(v);
            }
}

// ---------- queries GEMM with fused normalize + aspect-weight fold ----------
// qraw = hAbf @ wqT^T per aspect tile; norm over the 64 q-cols of the aspect
// lives inside the tile -> in-register reduce; store qwbf directly.
__global__ __launch_bounds__(64) void queries_mfma(
    const unsigned short* __restrict__ hAbf,   // [256][256]
    const unsigned short* __restrict__ wqT,    // [4*64][256] n-major
    const float* __restrict__ w,
    unsigned short* __restrict__ qwbf)         // [256][256]
{
    const int m0 = blockIdx.x * 32;
    const int a  = blockIdx.y;
    const unsigned short* B = wqT + (size_t)a * 64 * 256;
    const int l = threadIdx.x;
    const int q = l >> 4, l16 = l & 15;
    f32x4 acc[2][4] = {};
    for (int k0 = 0; k0 < 256; k0 += 32) {
        bf16x8 afr[2], bfr[4];
#pragma unroll
        for (int mt = 0; mt < 2; mt++)
            afr[mt] = *(const bf16x8*)&hAbf[(size_t)(m0 + mt * 16 + l16) * 256 + k0 + q * 8];
#pragma unroll
        for (int nt = 0; nt < 4; nt++)
            bfr[nt] = *(const bf16x8*)&B[(size_t)(nt * 16 + l16) * 256 + k0 + q * 8];
#pragma unroll
        for (int mt = 0; mt < 2; mt++)
#pragma unroll
            for (int nt = 0; nt < 4; nt++)
                acc[mt][nt] = __builtin_amdgcn_mfma_f32_16x16x32_bf16(
                    afr[mt], bfr[nt], acc[mt][nt], 0, 0, 0);
    }
    const float wa = w[a];
#pragma unroll
    for (int mt = 0; mt < 2; mt++) {
#pragma unroll
        for (int r = 0; r < 4; r++) {
            float ss = 0.f;
#pragma unroll
            for (int nt = 0; nt < 4; nt++) {
                float v = acc[mt][nt][r];
                ss += v * v;
            }
            ss += __shfl_xor(ss, 1, 64); ss += __shfl_xor(ss, 2, 64);
            ss += __shfl_xor(ss, 4, 64); ss += __shfl_xor(ss, 8, 64);
            float inv = wa / (sqrtf(ss) + 1e-8f);
            int b = m0 + mt * 16 + q * 4 + r;
#pragma unroll
            for (int nt = 0; nt < 4; nt++)
                qwbf[(size_t)b * 256 + a * 64 + nt * 16 + l16] = bfbits(acc[mt][nt][r] * inv);
        }
    }
}

// ---------- converts: pool -> bf16 row-major ----------
__global__ __launch_bounds__(256) void pool2bf(
    const void* __restrict__ pool, const int* __restrict__ flags,
    unsigned short* __restrict__ pb)
{
    const int fp = flags[IPOOL];
    const size_t total = (size_t)N_POOL * D_POOL;
    for (size_t i = ((size_t)blockIdx.x * 256 + threadIdx.x) * 4; i < total;
         i += (size_t)gridDim.x * 1024) {
        u16x4 o;
        if (fp == 0) {
            float4 v = *(const float4*)((const float*)pool + i);
            o[0] = bfbits(v.x); o[1] = bfbits(v.y); o[2] = bfbits(v.z); o[3] = bfbits(v.w);
        } else {
            o = *(const u16x4*)((const unsigned short*)pool + i);
        }
        *(u16x4*)&pb[i] = o;
    }
}

// ---------- generic fp32/bf16 -> bf16 row-major convert ----------
__global__ __launch_bounds__(256) void cvt2bf(
    const void* __restrict__ src, int fi, const int* __restrict__ flags,
    unsigned short* __restrict__ dst, int total)
{
    const int f = (fi >= 0) ? flags[fi] : 0;
    int i = (blockIdx.x * 256 + threadIdx.x) * 4;
    if (i >= total) return;
    if (f == 0) {
        float4 v = *(const float4*)((const float*)src + i);
        u16x4 o;
        o[0] = bfbits(v.x); o[1] = bfbits(v.y); o[2] = bfbits(v.z); o[3] = bfbits(v.w);
        *(u16x4*)&dst[i] = o;
    } else {
        *(u16x4*)&dst[i] = *(const u16x4*)((const unsigned short*)src + i);
    }
}

// ---------- transpose to bf16: dst[z][c][r] = src[z][r][c]; rows,cols mult of 64 ----------
__global__ __launch_bounds__(256) void transp_bf(
    const void* __restrict__ src, int fi, const int* __restrict__ flags,
    unsigned short* __restrict__ dst, int rows, int cols)
{
    const int f = (fi >= 0) ? flags[fi] : 0;
    const size_t zoff = (size_t)blockIdx.z * rows * cols;
    const int rb = blockIdx.y * 64, cb = blockIdx.x * 64;
    __shared__ float tile[64][65];
    const int t = threadIdx.x;
    const int lr = t >> 6, lc = t & 63;
#pragma unroll
    for (int i = 0; i < 16; i++) {
        int r = i * 4 + lr;
        tile[r][lc] = ldin(src, zoff + (size_t)(rb + r) * cols + cb + lc, f);
    }
    __syncthreads();
#pragma unroll
    for (int i = 0; i < 16; i++) {
        int c = i * 4 + lr;
        dst[zoff + (size_t)(cb + c) * rows + rb + lc] = bfbits(tile[lc][c]);
    }
}

// ---------- W_K fp32 [4][4608][64] -> bf16 n-major [4][64][4608] ----------
__global__ __launch_bounds__(256) void wk2bfT(
    const void* __restrict__ W_K, const int* __restrict__ flags,
    unsigned short* __restrict__ out)
{
    const int fk = flags[IWK];
    const int a = blockIdx.y, kb = blockIdx.x, t = threadIdx.x;
#pragma unroll
    for (int i = 0; i < 16; i++) {
        int idx = i * 256 + t;
        int kk = idx >> 6, qq = idx & 63;
        float v = ldin(W_K, (size_t)a * 294912 + (size_t)(kb * 64 + kk) * 64 + qq, fk);
        out[(size_t)(a * 64 + qq) * 4608 + kb * 64 + kk] = bfbits(v);
    }
}

// ---------- pool[:,4096:4352] -> bf16 col-major [256][2048] ----------
__global__ __launch_bounds__(256) void bias2bfT(
    const void* __restrict__ pool, const int* __restrict__ flags,
    unsigned short* __restrict__ out)
{
    const int fp = flags[IPOOL];
    const int nb = blockIdx.x, cb = blockIdx.y, t = threadIdx.x;
#pragma unroll
    for (int i = 0; i < 16; i++) {
        int idx = i * 256 + t;
        int nn = idx >> 6, cc = idx & 63;
        float v = ldin(pool, (size_t)(nb * 64 + nn) * 4608 + 4096 + cb * 64 + cc, fp);
        out[(size_t)(cb * 64 + cc) * 2048 + nb * 64 + nn] = bfbits(v);
    }
}

// ---------- C[i] = bias[i % N] (or 0) ----------
__global__ __launch_bounds__(256) void init_bias_kernel(
    float* __restrict__ C, const void* __restrict__ bias, int bifi,
    const int* __restrict__ flags, int N, int total)
{
    int i = blockIdx.x * 256 + threadIdx.x;
    if (i >= total) return;
    float v = 0.f;
    if (bias) v = ldin(bias, i % N, (bifi >= 0) ? flags[bifi] : 0);
    C[i] = v;
}

// ---------- per-(n,aspect) normalize -> bf16 ----------
__global__ __launch_bounds__(256) void knorm_kernel(
    const float* __restrict__ keys, unsigned short* __restrict__ knbf)
{
    const int n = blockIdx.x;
    const int a = threadIdx.x >> 6, q = threadIdx.x & 63;
    float v = keys[(size_t)n * 256 + a * 64 + q];
    float ss = wsum(v * v);
    knbf[(size_t)n * 256 + a * 64 + q] = bfbits(v / (sqrtf(ss) + 1e-8f));
}

// ---------- softmax over 4 aspect logits ----------
__global__ void softmax4_kernel(const void* __restrict__ logits,
                                const int* __restrict__ flags, float* __restrict__ w) {
    if (threadIdx.x == 0) {
        int f = flags[ILOG];
        float l0 = ldin(logits, 0, f), l1 = ldin(logits, 1, f);
        float l2 = ldin(logits, 2, f), l3 = ldin(logits, 3, f);
        float m = fmaxf(fmaxf(l0, l1), fmaxf(l2, l3));
        float e0 = expf(l0 - m), e1 = expf(l1 - m), e2 = expf(l2 - m), e3 = expf(l3 - m);
        float s = e0 + e1 + e2 + e3;
        w[0] = e0 / s; w[1] = e1 / s; w[2] = e2 / s; w[3] = e3 / s;
    }
}

// ---------- alpha: fp32 alpha (b-major, output) + bf16 alphaT (n-octet-major)
//            + bf16 alphaB (row-major) ----------
__global__ __launch_bounds__(256) void alpha_kernel(
    const float* __restrict__ scores, const void* __restrict__ tau_p,
    const int* __restrict__ flags,
    float* __restrict__ alpha_out, unsigned short* __restrict__ alphaT,
    unsigned short* __restrict__ alphaB)
{
    const int b = blockIdx.x;
    const int tid = threadIdx.x;
    const float tauv = ldin(tau_p, 0, flags[ITAU]);
    float ar[8];
    float lsum = 0.f;
#pragma unroll
    for (int i = 0; i < 8; i++) {
        int n = i * 256 + tid;
        float s = scores[b * 2048 + n];
        float g = 1.f / (1.f + expf(-(s - tauv)));  // LAMBDA_SHARP=1
        ar[i] = g * expf(s);                         // TEMPERATURE=1
        lsum += ar[i];
    }
    __shared__ float sb[4];
    float wsv = wsum(lsum);
    if ((tid & 63) == 0) sb[tid >> 6] = wsv;
    __syncthreads();
    float tot = sb[0] + sb[1] + sb[2] + sb[3];
    float inv = 1.f / (tot + 1e-8f);
#pragma unroll
    for (int i = 0; i < 8; i++) {
        int n = i * 256 + tid;
        float al = ar[i] * inv;
        alpha_out[b * 2048 + n] = al;
        unsigned short bb = bfbits(al);
        alphaT[(size_t)(n >> 3) * 2048 + b * 8 + (n & 7)] = bb;
        alphaB[(size_t)b * 2048 + n] = bb;
    }
}

// ---------- W_assembled via MFMA (v3 structure, + fused h_t partial) ----------
// Main loop identical to the proven round-4/5 version (140.5-141.4 us).
// Epilogue additionally computes ypart[b,c] += sum_e W[b,c,e]*hA[b,e] for the
// block's 16 e's (in-register values; removes hty's 67MB re-read of out_W).
#define QW 520  // shorts per cg block (260 dwords = 1040 B)
__global__ __launch_bounds__(256, 2) void assemble_mfma(
    const unsigned short* __restrict__ alphaT,  // bf16 [n/8][256 b][8]
    const void* __restrict__ pool,
    const void* __restrict__ W_base,
    const int* __restrict__ flags,
    float* __restrict__ Wout,                   // (256,256,256) fp32
    const float* __restrict__ hA,               // (256,256) fp32
    float* __restrict__ ypart)                  // (256,256) fp32, zero-initialized
{
    const int fp = flags[IPOOL], fw = flags[IWBASE];
    const int lid = blockIdx.x;
    const int xcd = lid & 7, idx = lid >> 3;
    const int dt = idx & 31;                    // 32 d-tiles
    const int et = ((idx >> 5) << 3) + xcd;     // 16 e-tiles; XCD owns {xcd, xcd+8}
    const int d0 = dt * 8, e0 = et * 16;
    const int t = threadIdx.x;
    const int w = t >> 6, l = t & 63;
    const int q = l >> 4, l16 = l & 15;

    const int nl  = t >> 3;                     // local n 0..31
    const int sub = t & 7;
    const int dlp = sub >> 1;                   // d rows dlp*2, dlp*2+1
    const int eh  = sub & 1;                    // e-half: el = eh*8 + i
    const int jj  = nl & 7;                     // n-octet slot (kq == w)

    __shared__ __align__(16) float Us[2][32][76];
    __shared__ __align__(16) float Vs[2][32][132];
    __shared__ __align__(16) unsigned short uvb[8][QW];

    const float4* pool4 = (const float4*)pool;

    f32x4 acc[4][8] = {};

    auto load_stage = [&](int n0, float4* st) {
#pragma unroll
        for (int i = 0; i < 2; i++) {
            int f = i * 256 + t;
            int n = n0 + (f >> 4);
            int q4 = f & 15;
            if (fp == 0) {
                st[i] = pool4[(size_t)n * 1152 + d0 * 2 + q4];
            } else {
                size_t base = (size_t)n * 4608 + (size_t)d0 * 8 + q4 * 4;
                st[i] = make_float4(ldin(pool, base, 1), ldin(pool, base + 1, 1),
                                    ldin(pool, base + 2, 1), ldin(pool, base + 3, 1));
            }
        }
#pragma unroll
        for (int i = 0; i < 4; i++) {
            int f = i * 256 + t;
            int n = n0 + (f >> 5);
            int r = (f & 31) >> 2, e4 = f & 3;
            if (fp == 0) {
                st[2 + i] = pool4[(size_t)n * 1152 + 512 + r * 64 + (e0 >> 2) + e4];
            } else {
                size_t base = (size_t)n * 4608 + 2048 + (size_t)r * 256 + e0 + e4 * 4;
                st[2 + i] = make_float4(ldin(pool, base, 1), ldin(pool, base + 1, 1),
                                        ldin(pool, base + 2, 1), ldin(pool, base + 3, 1));
            }
        }
    };
    auto store_stage = [&](int bp, const float4* st) {
#pragma unroll
        for (int i = 0; i < 2; i++) {
            int f = i * 256 + t;
            *(float4*)&Us[bp][f >> 4][(f & 15) * 4] = st[i];
        }
#pragma unroll
        for (int i = 0; i < 4; i++) {
            int f = i * 256 + t;
            int r = (f & 31) >> 2, e4 = f & 3;
            *(float4*)&Vs[bp][f >> 5][r * 16 + e4 * 4] = st[2 + i];
        }
    };

    {
        float4 st[6];
        load_stage(0, st);
        store_stage(0, st);
    }
    __syncthreads();

    int p = 0;
    for (int step = 0; step < 64; step++) {
        const int n0 = step * 32;
        float4 stn[6];
        if (step < 63) load_stage(n0 + 32, stn);

        bf16x8 afr[4];
#pragma unroll
        for (int mt = 0; mt < 4; mt++) {
            const unsigned short* ap =
                alphaT + (size_t)(step * 4 + q) * 2048 + (w * 64 + mt * 16 + l16) * 8;
            afr[mt] = *(const bf16x8*)ap;
        }

        {
            const float* Ur = &Us[p][nl][dlp * 16];
            float4 Ua = *(const float4*)(Ur);
            float4 Ub = *(const float4*)(Ur + 4);
            float4 Uc = *(const float4*)(Ur + 8);
            float4 Ud = *(const float4*)(Ur + 12);
            float U0[8] = {Ua.x, Ua.y, Ua.z, Ua.w, Ub.x, Ub.y, Ub.z, Ub.w};
            float U1[8] = {Uc.x, Uc.y, Uc.z, Uc.w, Ud.x, Ud.y, Ud.z, Ud.w};
            float uv0[8] = {0.f, 0.f, 0.f, 0.f, 0.f, 0.f, 0.f, 0.f};
            float uv1[8] = {0.f, 0.f, 0.f, 0.f, 0.f, 0.f, 0.f, 0.f};
#pragma unroll
            for (int r = 0; r < 8; r++) {
                float4 va = *(const float4*)&Vs[p][nl][r * 16 + eh * 8];
                float4 vb = *(const float4*)&Vs[p][nl][r * 16 + eh * 8 + 4];
                uv0[0] += U0[r] * va.x; uv0[1] += U0[r] * va.y;
                uv0[2] += U0[r] * va.z; uv0[3] += U0[r] * va.w;
                uv0[4] += U0[r] * vb.x; uv0[5] += U0[r] * vb.y;
                uv0[6] += U0[r] * vb.z; uv0[7] += U0[r] * vb.w;
                uv1[0] += U1[r] * va.x; uv1[1] += U1[r] * va.y;
                uv1[2] += U1[r] * va.z; uv1[3] += U1[r] * va.w;
                uv1[4] += U1[r] * vb.x; uv1[5] += U1[r] * vb.y;
                uv1[6] += U1[r] * vb.z; uv1[7] += U1[r] * vb.w;
            }
            const int cg0 = dlp * 2, cg1 = cg0 + 1;
            const int wbase = w * 128 + eh * 64 + jj;
#pragma unroll
            for (int i = 0; i < 8; i++) {
                uvb[cg0][wbase + i * 8] = bfbits(uv0[i]);
                uvb[cg1][wbase + i * 8] = bfbits(uv1[i]);
            }
        }
        __syncthreads();

        bf16x8 bfr[8];
#pragma unroll
        for (int cg = 0; cg < 8; cg++)
            bfr[cg] = *(const bf16x8*)&uvb[cg][l * 8];
        if (step < 63) store_stage(p ^ 1, stn);
#pragma unroll
        for (int mt = 0; mt < 4; mt++)
#pragma unroll
            for (int cg = 0; cg < 8; cg++)
                acc[mt][cg] = __builtin_amdgcn_mfma_f32_16x16x32_bf16(
                    afr[mt], bfr[cg], acc[mt][cg], 0, 0, 0);
        __syncthreads();
        p ^= 1;
    }

    float wb[8];
#pragma unroll
    for (int cg = 0; cg < 8; cg++)
        wb[cg] = ldin(W_base, (size_t)(d0 + cg) * 256 + e0 + l16, fw);

    // hA values for this thread's 16 b's at column e = e0 + l16
    float ha[4][4];
#pragma unroll
    for (int mt = 0; mt < 4; mt++)
#pragma unroll
        for (int r = 0; r < 4; r++)
            ha[mt][r] = hA[(size_t)(w * 64 + mt * 16 + q * 4 + r) * 256 + e0 + l16];

#pragma unroll
    for (int mt = 0; mt < 4; mt++) {
#pragma unroll
        for (int cg = 0; cg < 8; cg++) {
            size_t col = (size_t)(d0 + cg) * 256 + e0 + l16;
#pragma unroll
            for (int r = 0; r < 4; r++) {
                int b = w * 64 + mt * 16 + q * 4 + r;
                float v = acc[mt][cg][r] + wb[cg];
                Wout[(size_t)b * 65536 + col] = v;
                // fused h_t partial: reduce v*hA over the 16 e's (l16 lanes)
                float pp = v * ha[mt][r];
                pp += __shfl_xor(pp, 1, 64); pp += __shfl_xor(pp, 2, 64);
                pp += __shfl_xor(pp, 4, 64); pp += __shfl_xor(pp, 8, 64);
                if (l16 == 0)
                    atomicAdd(&ypart[(size_t)b * 256 + d0 + cg], pp);
            }
        }
    }
}

// ---------- layernorm over y = hA + gamma*(ypart + bass)  -> bf16 ----------
__global__ __launch_bounds__(256) void ln_kernel(
    const float* __restrict__ hA, const float* __restrict__ ypart,
    const float* __restrict__ bass, const void* __restrict__ gamma_p,
    const void* __restrict__ ln_scale, const void* __restrict__ ln_bias,
    const int* __restrict__ flags, unsigned short* __restrict__ hmidbf)
{
    const int fs = flags[ILNS], fb = flags[ILNB];
    const int b = blockIdx.x, tid = threadIdx.x;
    const int i = b * 256 + tid;
    float gm = ldin(gamma_p, 0, flags[IGAMMA]);
    float v = hA[i] + gm * (ypart[i] + bass[i]);
    __shared__ float s1b[4], s2b[4];
    float w1 = wsum(v), w2 = wsum(v * v);
    if ((tid & 63) == 0) { s1b[tid >> 6] = w1; s2b[tid >> 6] = w2; }
    __syncthreads();
    float mu = (s1b[0] + s1b[1] + s1b[2] + s1b[3]) * (1.f / 256.f);
    float ex2 = (s2b[0] + s2b[1] + s2b[2] + s2b[3]) * (1.f / 256.f);
    float var = ex2 - mu * mu;
    float inv = 1.f / sqrtf(var + 1e-6f);
    float hm = (v - mu) * inv * ldin(ln_scale, tid, fs) + ldin(ln_bias, tid, fb);
    hmidbf[b * 256 + tid] = bfbits(hm);
}

// ---------- launch ----------
extern "C" void kernel_launch(void* const* d_in, const int* in_sizes, int n_in,
                              void* d_out, int out_size, void* d_ws, size_t ws_size,
                              hipStream_t stream)
{
    (void)out_size; (void)n_in;
    const void* x      = d_in[0];
    const void* pool   = d_in[1];
    const void* A_w0   = d_in[2];
    const void* A_b0   = d_in[3];
    const void* A_w1   = d_in[4];
    const void* A_b1   = d_in[5];
    const void* W_Q    = d_in[6];
    const void* W_K    = d_in[7];
    const void* logits = d_in[8];
    const void* tau    = d_in[9];
    const void* W_base = d_in[10];
    const void* b_base = d_in[11];
    const void* gamma  = d_in[12];
    const void* ln_s   = d_in[13];
    const void* ln_b   = d_in[14];
    const void* B_w0   = d_in[15];
    const void* B_b0   = d_in[16];
    const void* B_w1   = d_in[17];
    const void* B_b1   = d_in[18];

    // Outputs: FP32, concatenated in return order.
    float* out       = (float*)d_out;
    float* out0      = out;               // (256,512)
    float* out_alpha = out + 131072;      // (256,2048)
    float* out_W     = out + 655360;      // (256,256,256) = 16.7M floats
    float* out_keys  = out + 17432576;    // (2048,4,64)

    // Small scratch, always in d_ws
    float* ws = (float*)d_ws;
    int*   flagp   = (int*)d_ws;          // ints [0,32)
    float* ws_w    = ws + 32;
    float* ws_hA   = ws + 64;             // 65536
    float* ws_bass = ws + 131136;         // 65536
    float* ypart   = ws + 196672;         // 65536 (was ws_y)
    unsigned short* hmidbf = (unsigned short*)(ws + 262208);    // 65536 sh
    unsigned short* alpha_bf = (unsigned short*)(ws + 327744);  // alphaT: 524288 bf16
    // small region ends at 589888 floats (2.36 MB)

    // Big slots: prefer d_ws; fall back to out_W region (dead until assemble).
    size_t wsf = ws_size / 4;
    bool full = wsf >= 1638464;
    float* slotA;   // scores
    float* slotB;   // knbf
    float* Treg;    // post-assemble scratch: T1bf + bw0T (262144 floats)
    float* scr = (float*)out_W;
    if (full) {
        slotA = ws + 589888;
        slotB = ws + 1114176;
        Treg  = ws + 589888;        // reused after assemble
    } else {
        slotA = scr;
        slotB = scr + 524288;
        Treg  = ws + 327744;        // alphaT region, dead after assemble
    }
    float* scores = slotA;                               // 524288 f
    unsigned short* knbf = (unsigned short*)slotB;       // 524288 sh
    unsigned short* T1bf = (unsigned short*)Treg;        // 262144 sh = 131072 f
    unsigned short* bw0T = (unsigned short*)(Treg + 131072);  // 262144 sh

    // bf16/fp32 staging buffers in the dead out_W region (all dead before assemble):
    unsigned short* xbf    = (unsigned short*)(scr + 1048576);   // 131072 sh
    unsigned short* aw0T   = (unsigned short*)(scr + 1114112);   // 524288 sh
    unsigned short* aw1T   = (unsigned short*)(scr + 1376256);   // 262144 sh
    unsigned short* wqT    = (unsigned short*)(scr + 1507328);   // 65536 sh
    unsigned short* Gbf    = (unsigned short*)(scr + 1540096);   // 262144 sh
    unsigned short* hAbf   = (unsigned short*)(scr + 1671168);   // 65536 sh
    unsigned short* qwbf   = (unsigned short*)(scr + 1769472);   // 65536 sh
    unsigned short* poolbf = (unsigned short*)(scr + 2097152);   // 9.44M sh
    unsigned short* wkbT   = (unsigned short*)(scr + 7340032);   // 1.18M sh
    unsigned short* biasT  = (unsigned short*)(scr + 8388608);   // 524288 sh
    unsigned short* alphaB = (unsigned short*)(scr + 8912896);   // 524288 sh

    // 0) per-input dtype detection
    P19 ip;
    for (int i = 0; i < 19; i++) { ip.p[i] = d_in[i]; ip.n[i] = in_sizes[i]; }
    detect_all<<<19, 256, 0, stream>>>(ip, flagp);
    // 1) aspect softmax
    softmax4_kernel<<<1, 64, 0, stream>>>(logits, flagp, ws_w);
    // 1b) bf16 converts / transposes for MFMA GEMMs
    pool2bf<<<2048, 256, 0, stream>>>(pool, flagp, poolbf);
    wk2bfT<<<dim3(72, 4), 256, 0, stream>>>(W_K, flagp, wkbT);
    bias2bfT<<<dim3(32, 4), 256, 0, stream>>>(pool, flagp, biasT);
    cvt2bf<<<128, 256, 0, stream>>>(x, IX, flagp, xbf, 131072);
    transp_bf<<<dim3(16, 8, 1), 256, 0, stream>>>(A_w0, IAW0, flagp, aw0T, 512, 1024);
    transp_bf<<<dim3(4, 16, 1), 256, 0, stream>>>(A_w1, IAW1, flagp, aw1T, 1024, 256);
    transp_bf<<<dim3(1, 4, 4), 256, 0, stream>>>(W_Q, IWQ, flagp, wqT, 256, 64);
    // 2) A-MLP via fused MFMA (1-wave blocks)
    gemm_mfma_fused<1><<<dim3(8, 16), 64, 0, stream>>>(
        xbf, 512, aw0T, 512, A_b0, IAB0, flagp, nullptr, Gbf, 1024, 512);
    gemm_mfma_fused<0><<<dim3(8, 4), 64, 0, stream>>>(
        Gbf, 1024, aw1T, 1024, A_b1, IAB1, flagp, ws_hA, hAbf, 256, 1024);
    // 3) keys = poolbf @ wkbT^T via MFMA split-K atomic (1-wave), then normalize -> knbf
    init_bias_kernel<<<2048, 256, 0, stream>>>(out_keys, nullptr, -1, flagp, 256, 524288);
    gemm_mfma_atomic<<<dim3(64, 4, 8), 64, 0, stream>>>(
        poolbf, 4608, wkbT, 4608, out_keys, 256, 576);
    knorm_kernel<<<2048, 256, 0, stream>>>(out_keys, knbf);
    // 4) queries with fused normalize + w[a] fold -> qwbf
    queries_mfma<<<dim3(8, 4), 64, 0, stream>>>(hAbf, wqT, ws_w, qwbf);
    // 5) scores = qwbf @ knbf^T (direct store)
    gemm_mfma_fused<0><<<dim3(8, 32), 64, 0, stream>>>(
        qwbf, 256, knbf, 256, nullptr, -1, flagp, scores, nullptr, 2048, 256);
    // 6) alpha -> out_alpha (fp32) + alphaT (n-octet bf16) + alphaB (row-major bf16)
    alpha_kernel<<<256, 256, 0, stream>>>(scores, tau, flagp, out_alpha, alpha_bf, alphaB);
    // 7) b_assembled = alpha @ biasT^T + b_base via MFMA split-K atomic (1-wave)
    init_bias_kernel<<<256, 256, 0, stream>>>(ws_bass, b_base, IBBASE, flagp, 256, 65536);
    gemm_mfma_atomic<<<dim3(8, 4, 8), 64, 0, stream>>>(
        alphaB, 2048, biasT, 2048, ws_bass, 256, 256);
    // 7b) zero h_t partial accumulator (before assemble)
    init_bias_kernel<<<256, 256, 0, stream>>>(ypart, nullptr, -1, flagp, 256, 65536);
    // 8) W_assembled via MFMA (dominant) + fused h_t partial into ypart
    assemble_mfma<<<512, 256, 0, stream>>>(alpha_bf, pool, W_base, flagp,
                                           out_W, ws_hA, ypart);
    // 8b) B_w0^T transpose (into post-assemble scratch; alphaT region now dead)
    transp_bf<<<dim3(16, 4, 1), 256, 0, stream>>>(B_w0, IBW0, flagp, bw0T, 256, 1024);
    // 9+10) y + layernorm fused -> bf16 (hty removed; uses ypart)
    ln_kernel<<<256, 256, 0, stream>>>(ws_hA, ypart, ws_bass, gamma,
                                       ln_s, ln_b, flagp, hmidbf);
    // 11) B-MLP1 via fused MFMA (gelu fused) -> T1 bf16
    gemm_mfma_fused<1><<<dim3(8, 16), 64, 0, stream>>>(
        hmidbf, 256, bw0T, 256, B_b0, IBB0, flagp, nullptr, T1bf, 1024, 256);
    // B-MLP2: fp32 split-K atomic reading bf16 T1 (afi=-2), fp32 B_w1
    init_bias_kernel<<<512, 256, 0, stream>>>(out0, B_b1, IBB1, flagp, 512, 131072);
    gemm64_splitk<0><<<dim3(8, 4, 4), 256, 0, stream>>>(
        T1bf, 1024, -2, B_w1, 512, IBW1, 0,
        out0, 512, 256, flagp);
}